// Round 3
// baseline (265.581 us; speedup 1.0000x reference)
//
#include <hip/hip_runtime.h>
#include <math.h>

// Problem constants (from reference setup_inputs)
constexpr int B = 16;
constexpr int S = 4096;
constexpr int F = 512;
constexpr int G = 16;      // outputs per emit group
constexpr int NG = 4;      // groups per thread
constexpr int L = G * NG;  // 64 outputs per thread
constexpr int BLOCK = 256; // threads per block; each thread owns TWO f columns (float2)

typedef float v2f __attribute__((ext_vector_type(2)));
static __device__ __forceinline__ v2f vs(float s) { return (v2f){s, s}; }

// out[b,t,f] = sum_i softmax(w)[i]/k_i * sum_{d=-p_i}^{p_i} x[b, clamp(t+d), f]
// Local-prefix-sum scheme, float2 per thread (8 B/lane -> 512 B per wave VMEM instr).
// prev[j] = P[T-16+j] (j=0..31), cur[j] = P[T+16+j] (j=0..15); emit 16 outputs/group.
__global__ __launch_bounds__(BLOCK, 4) void msavg_kernel(
    const float* __restrict__ x, const float* __restrict__ kw,
    float* __restrict__ out) {
  const int fpair = blockIdx.x * BLOCK + threadIdx.x;  // 0..255 -> f = 2*fpair
  const int t0    = blockIdx.y * L;                    // chunk start along S
  const int b     = blockIdx.z;

  // softmax over the 4 scale weights, folded with 1/k (uniform across threads)
  float w0 = kw[0], w1 = kw[1], w2 = kw[2], w3 = kw[3];
  float m  = fmaxf(fmaxf(w0, w1), fmaxf(w2, w3));
  float e0 = expf(w0 - m), e1 = expf(w1 - m), e2 = expf(w2 - m), e3 = expf(w3 - m);
  float inv = 1.0f / (e0 + e1 + e2 + e3);
  const float c3  = e0 * inv * (1.0f / 3.0f);
  const float c7  = e1 * inv * (1.0f / 7.0f);
  const float c15 = e2 * inv * (1.0f / 15.0f);
  const float c31 = e3 * inv * (1.0f / 31.0f);

  constexpr int RS = F / 2;  // row stride in float2 units
  const v2f* xb = (const v2f*)(x   + ((size_t)b * S) * F) + fpair;
  v2f*       ob = (v2f*)      (out + ((size_t)b * S) * F) + fpair;

  v2f prev[32];  // P[t0-16 .. t0+15]
  {
    v2f p = vs(0.0f);
#pragma unroll
    for (int j = 0; j < 32; ++j) {
      int s = t0 - 16 + j;
      s = s < 0 ? 0 : (s > S - 1 ? S - 1 : s);
      p += xb[(size_t)s * RS];
      prev[j] = p;
    }
  }

#pragma unroll
  for (int g = 0; g < NG; ++g) {
    const int T = t0 + g * G;

    // Load x rows T+16 .. T+31 (clamped at right edge)
    v2f xv[G];
    if (T + 16 + G - 1 <= S - 1) {
#pragma unroll
      for (int j = 0; j < G; ++j) xv[j] = xb[(size_t)(T + 16 + j) * RS];
    } else {
#pragma unroll
      for (int j = 0; j < G; ++j) {
        int s = T + 16 + j;
        s = s > S - 1 ? S - 1 : s;
        xv[j] = xb[(size_t)s * RS];
      }
    }

    // Extend prefix: cur[j] = P[T+16+j]
    v2f cur[G];
    {
      v2f p = prev[31];
#pragma unroll
      for (int j = 0; j < G; ++j) {
        p += xv[j];
        cur[j] = p;
      }
    }

    // Emit outputs t = T+j, j=0..15.
    // prev covers P[T-16..T+15], cur covers P[T+16..T+31].
#pragma unroll
    for (int j = 0; j < G; ++j) {
      v2f Pp15 = (j < 1)  ? prev[j + 31] : cur[j - 1];
      v2f Pp7  = (j < 9)  ? prev[j + 23] : cur[j - 9];
      v2f Pp3  = (j < 13) ? prev[j + 19] : cur[j - 13];
      v2f Pp1  = (j < 15) ? prev[j + 17] : cur[j - 15];
      v2f Pm2  = prev[j + 14];
      v2f Pm4  = prev[j + 12];
      v2f Pm8  = prev[j + 8];
      v2f Pm16 = prev[j];
      v2f o = vs(c3)  * (Pp1  - Pm2) +
              vs(c7)  * (Pp3  - Pm4) +
              vs(c15) * (Pp7  - Pm8) +
              vs(c31) * (Pp15 - Pm16);
      ob[(size_t)(T + j) * RS] = o;
    }

    // Roll the window: new prev = P[T'..] with T' = T+16
#pragma unroll
    for (int j = 0; j < 16; ++j) prev[j] = prev[j + 16];
#pragma unroll
    for (int j = 0; j < 16; ++j) prev[j + 16] = cur[j];
  }
}

extern "C" void kernel_launch(void* const* d_in, const int* in_sizes, int n_in,
                              void* d_out, int out_size, void* d_ws, size_t ws_size,
                              hipStream_t stream) {
  const float* x  = (const float*)d_in[0];  // [16, 4096, 512] fp32
  const float* kw = (const float*)d_in[1];  // [4] fp32
  float* out = (float*)d_out;               // [16, 4096, 512] fp32
  (void)in_sizes; (void)n_in; (void)out_size; (void)d_ws; (void)ws_size;

  dim3 grid((F / 2) / BLOCK, S / L, B);  // (1, 64, 16) = 1024 blocks
  msavg_kernel<<<grid, BLOCK, 0, stream>>>(x, kw, out);
}